// Round 8
// baseline (4430.178 us; speedup 1.0000x reference)
//
#include <hip/hip_runtime.h>
#include <hip/hip_fp16.h>

// LightGCN forward: 3 propagation layers + layer mean.
//
// Pipeline (no CSR; edge-centric layers):
//  1. msplit:   LDS-staged multisplit of edges into static per-bucket regions
//               (bucket = 1024 dst nodes, region CAP=18432 = mean+10sigma).
//               packed u32 = (dst&1023)<<19 | src. Cursor = qcur[b].
//  2. binfill2: per bucket: stage segment in LDS; dst-histogram -> rd/ird;
//               reorder edges stratum-ascending by src (src>>12 counting pass)
//               written back in place. Stratum order makes all layer blocks
//               sweep src-space in lockstep -> gathers hit a narrow L2 band.
//  3. init:     y0 = rd .* x0 (fp16 rows, 64B)
//  4. layerE x3: one block per bucket, fp32 accumulator in LDS (1024x33 padded),
//               stream bucket edges, gather y[src] (64B/edge), LDS atomic add;
//               writeback y_next = rd^2 * acc (fp16).
//  5. merge:    out = 0.25*(x0 + (y1+y2+y3)*sqrt(deg))
//
// Sorting/banding is a perf hint only; correctness independent of scheduling.

#define D 32
#define TILE 8192
#define MAXB 512
#define CAP 18432      // per-bucket capacity: mean 17067, sigma 130 -> +10.5 sigma
#define NSTRATA 128    // src>>12 -> 0..73

// ---------- 1. LDS-staged multisplit into static bucket regions ----------
__global__ void __launch_bounds__(256)
msplit_kernel(const int* __restrict__ src, const int* __restrict__ dst, int E, int nb,
              int* __restrict__ qcur, unsigned* __restrict__ estrm) {
    __shared__ unsigned buf[TILE];
    __shared__ int hist[MAXB], exc[MAXB], gbase[MAXB], off[MAXB], sc[MAXB];
    int t = threadIdx.x;
    int tile0 = blockIdx.x * TILE;
    if (tile0 >= E) return;
    int cnt = min(TILE, E - tile0);

    for (int i = t; i < MAXB; i += 256) hist[i] = 0;
    __syncthreads();
    for (int i = t; i < cnt; i += 256)
        atomicAdd(&hist[dst[tile0 + i] >> 10], 1);
    __syncthreads();

    // inclusive scan of hist[0..MAXB) with 256 threads (2 elems each)
    int h0 = hist[t], h1 = hist[t + 256];
    sc[t] = h0; sc[t + 256] = h1;
    __syncthreads();
    for (int o = 1; o < MAXB; o <<= 1) {
        int a0 = (t >= o) ? sc[t - o] : 0;
        int a1 = (t + 256 >= o) ? sc[t + 256 - o] : 0;
        __syncthreads();
        sc[t] += a0; sc[t + 256] += a1;
        __syncthreads();
    }
    exc[t] = sc[t] - h0;
    exc[t + 256] = sc[t + 256] - h1;
    gbase[t]       = (h0 > 0) ? (t * CAP + atomicAdd(&qcur[t], h0))             : 0;
    gbase[t + 256] = (h1 > 0) ? ((t + 256) * CAP + atomicAdd(&qcur[t + 256], h1)) : 0;
    off[t] = exc[t];
    off[t + 256] = exc[t + 256];
    __syncthreads();

    // group tile's edges by bucket in LDS
    for (int i = t; i < cnt; i += 256) {
        int d = dst[tile0 + i];              // L2-warm re-read
        int s = src[tile0 + i];
        int b = d >> 10;
        int pos = atomicAdd(&off[b], 1);
        buf[pos] = ((unsigned)(d & 1023) << 19) | (unsigned)s;
    }
    __syncthreads();

    // copy out: contiguous per-bucket segments -> coalesced global writes
    for (int i = t; i < cnt; i += 256) {
        int lo = 0, hi = nb - 1;             // largest b with exc[b] <= i
        while (lo < hi) { int mid = (lo + hi + 1) >> 1; if (exc[mid] <= i) lo = mid; else hi = mid - 1; }
        estrm[gbase[lo] + (i - exc[lo])] = buf[i];
    }
}

// ---------- 2. per-bucket: node stats + stratum reorder (in place) ----------
__global__ void __launch_bounds__(256)
binfill2_kernel(unsigned* __restrict__ estrm, const int* __restrict__ ecnt,
                int n, float* __restrict__ rd, float* __restrict__ ird) {
    int b = blockIdx.x;
    int lo = b << 10;
    int nn = min(1024, n - lo);
    int base = b * CAP;
    int cnt = ecnt[b];
    __shared__ unsigned ebuf[CAP];
    __shared__ int dcnt[1024];
    __shared__ int scnt[NSTRATA], soff[NSTRATA];
    int t = threadIdx.x;
    for (int i = t; i < 1024; i += 256) dcnt[i] = 0;
    for (int i = t; i < NSTRATA; i += 256) scnt[i] = 0;
    __syncthreads();
    for (int i = t; i < cnt; i += 256) {
        unsigned pk = estrm[base + i];
        ebuf[i] = pk;
        atomicAdd(&dcnt[pk >> 19], 1);
        atomicAdd(&scnt[(pk & 0x7FFFF) >> 12], 1);
    }
    __syncthreads();
    for (int i = t; i < nn; i += 256) {
        int c = dcnt[i];
        rd[lo + i]  = (c > 0) ? rsqrtf((float)c) : 0.0f;
        ird[lo + i] = (c > 0) ? sqrtf((float)c)  : 0.0f;
    }
    if (t == 0) {                        // tiny serial exclusive scan (128)
        int run = 0;
        for (int s = 0; s < NSTRATA; ++s) { int c = scnt[s]; soff[s] = run; run += c; }
    }
    __syncthreads();
    // scatter back stratum-ascending (random within stratum = fine)
    for (int i = t; i < cnt; i += 256) {
        unsigned pk = ebuf[i];
        int p = atomicAdd(&soff[(pk & 0x7FFFF) >> 12], 1);
        estrm[base + p] = pk;
    }
}

// ---------- 3. init y0 = rd .* x0 (fp16) ----------
__global__ void init_kernel(const float* __restrict__ ue, const float* __restrict__ ie,
                            const float* __restrict__ rd, int nu32, int tot32,
                            __half* __restrict__ y0) {
    int gid = blockIdx.x * blockDim.x + threadIdx.x;
    int i2 = gid * 2;
    if (i2 < tot32) {
        float v0 = (i2 < nu32) ? ue[i2] : ie[i2 - nu32];
        float v1 = (i2 < nu32) ? ue[i2 + 1] : ie[i2 + 1 - nu32];   // nu32 even
        float r = rd[i2 >> 5];
        *reinterpret_cast<__half2*>(y0 + i2) = __floats2half2_rn(r * v0, r * v1);
    }
}

// ---------- 4. edge-centric layer: LDS fp32 accumulate per bucket ----------
// y_next[i] = rd[i]^2 * sum_{e: dst=i} y[src]
__global__ void __launch_bounds__(1024)
layerE_kernel(const unsigned* __restrict__ estrm, const int* __restrict__ ecnt,
              const float* __restrict__ rd, const __half* __restrict__ yin,
              __half* __restrict__ yout, int n) {
    int b = blockIdx.x;
    int lo = b << 10;
    int nn = min(1024, n - lo);
    __shared__ float acc[1024 * 33];           // 33-dword pitch: bank spread
    int t = threadIdx.x;
    int q = t & 7;
    for (int i = t; i < 1024 * 33; i += 1024) acc[i] = 0.0f;
    __syncthreads();
    int base = b * CAP;
    int cnt = ecnt[b];
    int cap = (cnt + 1023) & ~1023;
    for (int i = t; i < cap; i += 1024) {
        unsigned ed = (i < cnt) ? estrm[base + i] : 0xFFFFFFFFu;
        #pragma unroll
        for (int j = 0; j < 8; ++j) {
            unsigned ej = __shfl(ed, j, 8);
            if (ej != 0xFFFFFFFFu) {
                int srcn = (int)(ej & 0x7FFFF);
                int dlo  = (int)(ej >> 19);
                uint2 u = *reinterpret_cast<const uint2*>(yin + srcn * D + q * 4);
                float2 f0 = __half22float2(*reinterpret_cast<__half2*>(&u.x));
                float2 f1 = __half22float2(*reinterpret_cast<__half2*>(&u.y));
                float* ap = &acc[dlo * 33 + q * 4];
                atomicAdd(ap + 0, f0.x);
                atomicAdd(ap + 1, f0.y);
                atomicAdd(ap + 2, f1.x);
                atomicAdd(ap + 3, f1.y);
            }
        }
    }
    __syncthreads();
    if (t < nn) {
        float r = rd[lo + t];
        float r2 = r * r;
        const float* ap = &acc[t * 33];
        #pragma unroll
        for (int k8 = 0; k8 < 4; ++k8) {
            __half2 h0 = __floats2half2_rn(r2 * ap[k8*8+0], r2 * ap[k8*8+1]);
            __half2 h1 = __floats2half2_rn(r2 * ap[k8*8+2], r2 * ap[k8*8+3]);
            __half2 h2 = __floats2half2_rn(r2 * ap[k8*8+4], r2 * ap[k8*8+5]);
            __half2 h3 = __floats2half2_rn(r2 * ap[k8*8+6], r2 * ap[k8*8+7]);
            uint4 w;
            w.x = *reinterpret_cast<unsigned*>(&h0);
            w.y = *reinterpret_cast<unsigned*>(&h1);
            w.z = *reinterpret_cast<unsigned*>(&h2);
            w.w = *reinterpret_cast<unsigned*>(&h3);
            *reinterpret_cast<uint4*>(yout + (size_t)(lo + t) * D + k8 * 8) = w;
        }
    }
}

// ---------- 5. merge: out = 0.25*(x0 + (y1+y2+y3)*ird) ----------
__global__ void merge_kernel(const float* __restrict__ ue, const float* __restrict__ ie,
                             const float* __restrict__ ird,
                             const __half* __restrict__ y1, const __half* __restrict__ y2,
                             const __half* __restrict__ y3,
                             int nu32, int tot32, float* __restrict__ out) {
    int gid = blockIdx.x * blockDim.x + threadIdx.x;
    int i2 = gid * 2;
    if (i2 < tot32) {
        float v0 = (i2 < nu32) ? ue[i2] : ie[i2 - nu32];
        float v1 = (i2 < nu32) ? ue[i2 + 1] : ie[i2 + 1 - nu32];
        float iv = ird[i2 >> 5];
        float2 a = __half22float2(*reinterpret_cast<const __half2*>(y1 + i2));
        float2 b = __half22float2(*reinterpret_cast<const __half2*>(y2 + i2));
        float2 c = __half22float2(*reinterpret_cast<const __half2*>(y3 + i2));
        float o0 = 0.25f * (v0 + (a.x + b.x + c.x) * iv);
        float o1 = 0.25f * (v1 + (a.y + b.y + c.y) * iv);
        *reinterpret_cast<float2*>(out + i2) = make_float2(o0, o1);
    }
}

extern "C" void kernel_launch(void* const* d_in, const int* in_sizes, int n_in,
                              void* d_out, int out_size, void* d_ws, size_t ws_size,
                              hipStream_t stream) {
    const int*   edge = (const int*)d_in[0];
    const float* ue   = (const float*)d_in[3];
    const float* ie   = (const float*)d_in[4];
    int E  = in_sizes[0] / 2;
    int nu = in_sizes[3] / D;
    int ni = in_sizes[4] / D;
    int n  = nu + ni;
    int nb = (n + 1023) >> 10;      // 293 buckets (<= MAXB)
    const int* src = edge;
    const int* dst = edge + E;
    float* out = (float*)d_out;

    // workspace layout (~81 MB)
    char* p = (char*)d_ws;
    int*      qcur  = (int*)p;      p += (MAXB + 1) * 4;
    float*    rd    = (float*)p;    p += (size_t)n * 4;
    float*    ird   = (float*)p;    p += (size_t)n * 4;
    unsigned* estrm = (unsigned*)p; p += (size_t)nb * CAP * 4;
    __half*   yA    = (__half*)p;   p += (size_t)n * D * 2;
    __half*   yB    = (__half*)p;   p += (size_t)n * D * 2;
    __half*   yC    = (__half*)p;   p += (size_t)n * D * 2;

    hipMemsetAsync(qcur, 0, (MAXB + 1) * 4, stream);

    msplit_kernel<<<(E + TILE - 1) / TILE, 256, 0, stream>>>(src, dst, E, nb, qcur, estrm);
    binfill2_kernel<<<nb, 256, 0, stream>>>(estrm, qcur, n, rd, ird);

    int tot32 = n * D;
    init_kernel<<<(n * 16 + 255) / 256, 256, 0, stream>>>(ue, ie, rd, nu * D, tot32, yA);

    layerE_kernel<<<nb, 1024, 0, stream>>>(estrm, qcur, rd, yA, yB, n);  // y1
    layerE_kernel<<<nb, 1024, 0, stream>>>(estrm, qcur, rd, yB, yC, n);  // y2
    layerE_kernel<<<nb, 1024, 0, stream>>>(estrm, qcur, rd, yC, yA, n);  // y3

    merge_kernel<<<(n * 16 + 255) / 256, 256, 0, stream>>>(ue, ie, ird, yB, yC, yA,
                                                           nu * D, tot32, out);
}

// Round 9
// 3048.622 us; speedup vs baseline: 1.4532x; 1.4532x over previous
//
#include <hip/hip_runtime.h>
#include <hip/hip_fp16.h>

// LightGCN forward: 3 propagation layers + layer mean.
//
// Pipeline (edge-centric layers, 128-node dst buckets):
//  1. msplit:   LDS-staged multisplit of edges into static per-bucket regions
//               (bucket = 128 dst nodes, CAP=2560 = mean+9sigma).
//               packed u32 = (dst&127)<<19 | src.
//  2. binfill2: per bucket: dst-histogram -> rd/ird; reorder edges
//               stratum-ascending by src (src>>12 counting pass). Stratum order
//               makes all layer blocks sweep src-space in lockstep -> gathers
//               hit a narrow L2 band (R8-verified: FETCH 407->196 MB).
//  3. init:     y0 = rd .* x0 (fp16 rows, 64B)
//  4. layerE x3: one block(128 thr)/bucket, fp32 acc in LDS (128x33 pitch);
//               LANE-OWNS-EDGE: 4x uint4 row load (MLP=4, no shfl/branch),
//               32 unrolled ds_add_f32. 16.9KB LDS -> 9 blocks/CU.
//  5. merge:    out = 0.25*(x0 + (y1+y2+y3)*sqrt(deg))
//
// Stratum order is a perf hint only; correctness independent of scheduling.

#define D 32
#define TILE 8192
#define BNODES 128          // nodes per bucket (BSHIFT=7)
#define MAXB2 2560          // >= nb = ceil(300000/128) = 2344
#define SPT 10              // MAXB2 / 256
#define CAP 2560            // per-bucket region: mean 2133, sigma 46 -> +9.2 sigma
#define NSTRATA 128         // src>>12 -> 0..73

// ---------- 1. LDS-staged multisplit into static bucket regions ----------
__global__ void __launch_bounds__(256)
msplit_kernel(const int* __restrict__ src, const int* __restrict__ dst, int E, int nb,
              int* __restrict__ qcur, unsigned* __restrict__ estrm) {
    __shared__ unsigned buf[TILE];
    __shared__ int hist[MAXB2], exc_[MAXB2], gbase[MAXB2], off[MAXB2];
    __shared__ int wsum[256];
    int t = threadIdx.x;
    int tile0 = blockIdx.x * TILE;
    if (tile0 >= E) return;
    int cnt = min(TILE, E - tile0);

    for (int i = t; i < MAXB2; i += 256) hist[i] = 0;
    __syncthreads();
    for (int i = t; i < cnt; i += 256)
        atomicAdd(&hist[dst[tile0 + i] >> 7], 1);
    __syncthreads();

    // two-level exclusive scan: per-thread SPT slots + 256-wide LDS scan
    int lsum = 0;
    #pragma unroll
    for (int s = 0; s < SPT; ++s) lsum += hist[t * SPT + s];
    wsum[t] = lsum;
    __syncthreads();
    for (int o = 1; o < 256; o <<= 1) {
        int a = (t >= o) ? wsum[t - o] : 0;
        __syncthreads();
        wsum[t] += a;
        __syncthreads();
    }
    int run = (t > 0) ? wsum[t - 1] : 0;
    #pragma unroll
    for (int s = 0; s < SPT; ++s) {
        int b = t * SPT + s;
        int h = hist[b];
        exc_[b] = run;
        off[b]  = run;
        run += h;
        gbase[b] = (h > 0) ? (b * CAP + atomicAdd(&qcur[b], h)) : 0;
    }
    __syncthreads();

    // group tile's edges by bucket in LDS
    for (int i = t; i < cnt; i += 256) {
        int d = dst[tile0 + i];              // L2-warm re-read
        int s = src[tile0 + i];
        int b = d >> 7;
        int pos = atomicAdd(&off[b], 1);
        buf[pos] = ((unsigned)(d & (BNODES - 1)) << 19) | (unsigned)s;
    }
    __syncthreads();

    // copy out: contiguous per-bucket segments -> coalesced global writes
    for (int i = t; i < cnt; i += 256) {
        int lo = 0, hi = nb - 1;             // largest b with exc_[b] <= i
        while (lo < hi) { int mid = (lo + hi + 1) >> 1; if (exc_[mid] <= i) lo = mid; else hi = mid - 1; }
        estrm[gbase[lo] + (i - exc_[lo])] = buf[i];
    }
}

// ---------- 2. per-bucket: node stats + stratum reorder (in place) ----------
__global__ void __launch_bounds__(256)
binfill2_kernel(unsigned* __restrict__ estrm, const int* __restrict__ ecnt,
                int n, float* __restrict__ rd, float* __restrict__ ird) {
    int b = blockIdx.x;
    int lo = b << 7;
    int nn = min(BNODES, n - lo);
    int base = b * CAP;
    int cnt = ecnt[b];
    __shared__ unsigned ebuf[CAP];
    __shared__ int dcnt[BNODES];
    __shared__ int scnt[NSTRATA], soff[NSTRATA];
    int t = threadIdx.x;
    if (t < BNODES) dcnt[t] = 0;
    if (t < NSTRATA) scnt[t] = 0;
    __syncthreads();
    for (int i = t; i < cnt; i += 256) {
        unsigned pk = estrm[base + i];
        ebuf[i] = pk;
        atomicAdd(&dcnt[pk >> 19], 1);
        atomicAdd(&scnt[(pk & 0x7FFFF) >> 12], 1);
    }
    __syncthreads();
    if (t < nn) {
        int c = dcnt[t];
        rd[lo + t]  = (c > 0) ? rsqrtf((float)c) : 0.0f;
        ird[lo + t] = (c > 0) ? sqrtf((float)c)  : 0.0f;
    }
    if (t == 0) {                        // tiny serial exclusive scan (128)
        int run = 0;
        for (int s = 0; s < NSTRATA; ++s) { int c = scnt[s]; soff[s] = run; run += c; }
    }
    __syncthreads();
    // scatter back stratum-ascending (random within stratum = fine)
    for (int i = t; i < cnt; i += 256) {
        unsigned pk = ebuf[i];
        int p = atomicAdd(&soff[(pk & 0x7FFFF) >> 12], 1);
        estrm[base + p] = pk;
    }
}

// ---------- 3. init y0 = rd .* x0 (fp16) ----------
__global__ void init_kernel(const float* __restrict__ ue, const float* __restrict__ ie,
                            const float* __restrict__ rd, int nu32, int tot32,
                            __half* __restrict__ y0) {
    int gid = blockIdx.x * blockDim.x + threadIdx.x;
    int i2 = gid * 2;
    if (i2 < tot32) {
        float v0 = (i2 < nu32) ? ue[i2] : ie[i2 - nu32];
        float v1 = (i2 < nu32) ? ue[i2 + 1] : ie[i2 + 1 - nu32];   // nu32 even
        float r = rd[i2 >> 5];
        *reinterpret_cast<__half2*>(y0 + i2) = __floats2half2_rn(r * v0, r * v1);
    }
}

// ---------- 4. edge-centric layer: lane-owns-edge, LDS fp32 accumulate ----------
// y_next[i] = rd[i]^2 * sum_{e: dst=i} y[src]
__device__ __forceinline__ void add8(float* ap, uint4 u) {
    float2 f;
    f = __half22float2(*reinterpret_cast<__half2*>(&u.x));
    atomicAdd(ap + 0, f.x); atomicAdd(ap + 1, f.y);
    f = __half22float2(*reinterpret_cast<__half2*>(&u.y));
    atomicAdd(ap + 2, f.x); atomicAdd(ap + 3, f.y);
    f = __half22float2(*reinterpret_cast<__half2*>(&u.z));
    atomicAdd(ap + 4, f.x); atomicAdd(ap + 5, f.y);
    f = __half22float2(*reinterpret_cast<__half2*>(&u.w));
    atomicAdd(ap + 6, f.x); atomicAdd(ap + 7, f.y);
}

__global__ void __launch_bounds__(128)
layerE_kernel(const unsigned* __restrict__ estrm, const int* __restrict__ ecnt,
              const float* __restrict__ rd, const __half* __restrict__ yin,
              __half* __restrict__ yout, int n) {
    int b = blockIdx.x;
    int lo = b << 7;
    int nn = min(BNODES, n - lo);
    __shared__ float acc[BNODES * 33];         // 33-dword pitch: bank spread
    int t = threadIdx.x;
    #pragma unroll
    for (int k = 0; k < 33; ++k) acc[k * BNODES + t] = 0.0f;
    __syncthreads();
    int base = b * CAP;
    int cnt = ecnt[b];
    for (int i = t; i < cnt; i += 128) {
        unsigned pk = estrm[base + i];
        int dlo  = (int)(pk >> 19);
        int srcn = (int)(pk & 0x7FFFF);
        const uint4* yp = reinterpret_cast<const uint4*>(yin + (size_t)srcn * D);
        uint4 u0 = yp[0], u1 = yp[1], u2 = yp[2], u3 = yp[3];   // 64B row, MLP=4
        float* ap = &acc[dlo * 33];
        add8(ap +  0, u0);
        add8(ap +  8, u1);
        add8(ap + 16, u2);
        add8(ap + 24, u3);
    }
    __syncthreads();
    if (t < nn) {
        float r = rd[lo + t];
        float r2 = r * r;
        const float* ap = &acc[t * 33];
        #pragma unroll
        for (int k8 = 0; k8 < 4; ++k8) {
            __half2 h0 = __floats2half2_rn(r2 * ap[k8*8+0], r2 * ap[k8*8+1]);
            __half2 h1 = __floats2half2_rn(r2 * ap[k8*8+2], r2 * ap[k8*8+3]);
            __half2 h2 = __floats2half2_rn(r2 * ap[k8*8+4], r2 * ap[k8*8+5]);
            __half2 h3 = __floats2half2_rn(r2 * ap[k8*8+6], r2 * ap[k8*8+7]);
            uint4 w;
            w.x = *reinterpret_cast<unsigned*>(&h0);
            w.y = *reinterpret_cast<unsigned*>(&h1);
            w.z = *reinterpret_cast<unsigned*>(&h2);
            w.w = *reinterpret_cast<unsigned*>(&h3);
            *reinterpret_cast<uint4*>(yout + (size_t)(lo + t) * D + k8 * 8) = w;
        }
    }
}

// ---------- 5. merge: out = 0.25*(x0 + (y1+y2+y3)*ird) ----------
__global__ void merge_kernel(const float* __restrict__ ue, const float* __restrict__ ie,
                             const float* __restrict__ ird,
                             const __half* __restrict__ y1, const __half* __restrict__ y2,
                             const __half* __restrict__ y3,
                             int nu32, int tot32, float* __restrict__ out) {
    int gid = blockIdx.x * blockDim.x + threadIdx.x;
    int i2 = gid * 2;
    if (i2 < tot32) {
        float v0 = (i2 < nu32) ? ue[i2] : ie[i2 - nu32];
        float v1 = (i2 < nu32) ? ue[i2 + 1] : ie[i2 + 1 - nu32];
        float iv = ird[i2 >> 5];
        float2 a = __half22float2(*reinterpret_cast<const __half2*>(y1 + i2));
        float2 b = __half22float2(*reinterpret_cast<const __half2*>(y2 + i2));
        float2 c = __half22float2(*reinterpret_cast<const __half2*>(y3 + i2));
        float o0 = 0.25f * (v0 + (a.x + b.x + c.x) * iv);
        float o1 = 0.25f * (v1 + (a.y + b.y + c.y) * iv);
        *reinterpret_cast<float2*>(out + i2) = make_float2(o0, o1);
    }
}

static inline char* alloc256(char*& p, size_t bytes) {
    uintptr_t q = ((uintptr_t)p + 255) & ~(uintptr_t)255;
    char* r = (char*)q;
    p = r + bytes;
    return r;
}

extern "C" void kernel_launch(void* const* d_in, const int* in_sizes, int n_in,
                              void* d_out, int out_size, void* d_ws, size_t ws_size,
                              hipStream_t stream) {
    const int*   edge = (const int*)d_in[0];
    const float* ue   = (const float*)d_in[3];
    const float* ie   = (const float*)d_in[4];
    int E  = in_sizes[0] / 2;
    int nu = in_sizes[3] / D;
    int ni = in_sizes[4] / D;
    int n  = nu + ni;
    int nb = (n + BNODES - 1) >> 7;          // 2344 (<= MAXB2)
    const int* src = edge;
    const int* dst = edge + E;
    float* out = (float*)d_out;

    // workspace layout (~63 MB), all 256B-aligned (uint4 paths need 16B)
    char* p = (char*)d_ws;
    int*      qcur  = (int*)alloc256(p, (size_t)(MAXB2 + 1) * 4);
    float*    rd    = (float*)alloc256(p, (size_t)n * 4);
    float*    ird   = (float*)alloc256(p, (size_t)n * 4);
    unsigned* estrm = (unsigned*)alloc256(p, (size_t)nb * CAP * 4);
    __half*   yA    = (__half*)alloc256(p, (size_t)n * D * 2);
    __half*   yB    = (__half*)alloc256(p, (size_t)n * D * 2);
    __half*   yC    = (__half*)alloc256(p, (size_t)n * D * 2);

    hipMemsetAsync(qcur, 0, (size_t)(MAXB2 + 1) * 4, stream);

    msplit_kernel<<<(E + TILE - 1) / TILE, 256, 0, stream>>>(src, dst, E, nb, qcur, estrm);
    binfill2_kernel<<<nb, 256, 0, stream>>>(estrm, qcur, n, rd, ird);

    int tot32 = n * D;
    init_kernel<<<(n * 16 + 255) / 256, 256, 0, stream>>>(ue, ie, rd, nu * D, tot32, yA);

    layerE_kernel<<<nb, 128, 0, stream>>>(estrm, qcur, rd, yA, yB, n);  // y1
    layerE_kernel<<<nb, 128, 0, stream>>>(estrm, qcur, rd, yB, yC, n);  // y2
    layerE_kernel<<<nb, 128, 0, stream>>>(estrm, qcur, rd, yC, yA, n);  // y3

    merge_kernel<<<(n * 16 + 255) / 256, 256, 0, stream>>>(ue, ie, ird, yB, yC, yA,
                                                           nu * D, tot32, out);
}

// Round 11
// 657.483 us; speedup vs baseline: 6.7381x; 4.6368x over previous
//
#include <hip/hip_runtime.h>
#include <hip/hip_fp16.h>

// LightGCN forward: 3 propagation layers + layer mean.
//
// Pipeline:
//  1. msplit:   LDS-staged multisplit of edges into static per-bucket regions
//               (bucket = 128 dst nodes, CAP=2560 = mean+9sigma).
//               packed u32 = (dst&127)<<19 | src.
//  2. binfill3: per bucket: two-key LDS counting sort (key = dlo<<6 | src>>13)
//               -> col grouped by dst row, ascending src within row; writes
//               rstart/rlen/rd/ird. Row-ascending src order makes all
//               concurrent gather groups sweep src-space in lockstep ->
//               narrow L2 band (R8-verified: FETCH 407->196 MB).
//  3. init:     y0 = rd .* x0 (fp16 rows, 64B)
//  4. layer x3: node-centric CSR gather (R7-proven execution): 8-lane group
//               per node, lane q = feature quad; cooperative col load + shfl.
//               y_next[i] = rd[i]^2 * sum_{src in row i} y[src]
//  5. merge:    out = 0.25*(x0 + (y1+y2+y3)*sqrt(deg))
//
// Sort order is a perf hint only; correctness independent of scheduling.

#define D 32
#define TILE 8192
#define BNODES 128          // nodes per bucket (shift 7)
#define MAXB2 2560          // >= nb = ceil(300000/128) = 2344
#define SPT 10              // MAXB2 / 256
#define CAP 2560            // per-bucket region: mean 2133, sigma 46 -> +9.2 sigma
#define NKEY 8192           // 128 dlo x 64 src-strata (src>>13 -> 0..36)
#define KPT 32              // NKEY / 256

// ---------- 1. LDS-staged multisplit into static bucket regions ----------
__global__ void __launch_bounds__(256)
msplit_kernel(const int* __restrict__ src, const int* __restrict__ dst, int E, int nb,
              int* __restrict__ qcur, unsigned* __restrict__ estrm) {
    __shared__ unsigned buf[TILE];
    __shared__ int hist[MAXB2], exc_[MAXB2], gbase[MAXB2], off[MAXB2];
    __shared__ int wsum[256];
    int t = threadIdx.x;
    int tile0 = blockIdx.x * TILE;
    if (tile0 >= E) return;
    int cnt = min(TILE, E - tile0);

    for (int i = t; i < MAXB2; i += 256) hist[i] = 0;
    __syncthreads();
    for (int i = t; i < cnt; i += 256)
        atomicAdd(&hist[dst[tile0 + i] >> 7], 1);
    __syncthreads();

    // two-level exclusive scan: per-thread SPT slots + 256-wide LDS scan
    int lsum = 0;
    #pragma unroll
    for (int s = 0; s < SPT; ++s) lsum += hist[t * SPT + s];
    wsum[t] = lsum;
    __syncthreads();
    for (int o = 1; o < 256; o <<= 1) {
        int a = (t >= o) ? wsum[t - o] : 0;
        __syncthreads();
        wsum[t] += a;
        __syncthreads();
    }
    int run = (t > 0) ? wsum[t - 1] : 0;
    #pragma unroll
    for (int s = 0; s < SPT; ++s) {
        int b = t * SPT + s;
        int h = hist[b];
        exc_[b] = run;
        off[b]  = run;
        run += h;
        gbase[b] = (h > 0) ? (b * CAP + atomicAdd(&qcur[b], h)) : 0;
    }
    __syncthreads();

    // group tile's edges by bucket in LDS
    for (int i = t; i < cnt; i += 256) {
        int d = dst[tile0 + i];              // L2-warm re-read
        int s = src[tile0 + i];
        int b = d >> 7;
        int pos = atomicAdd(&off[b], 1);
        buf[pos] = ((unsigned)(d & (BNODES - 1)) << 19) | (unsigned)s;
    }
    __syncthreads();

    // copy out: contiguous per-bucket segments -> coalesced global writes
    for (int i = t; i < cnt; i += 256) {
        int lo = 0, hi = nb - 1;             // largest b with exc_[b] <= i
        while (lo < hi) { int mid = (lo + hi + 1) >> 1; if (exc_[mid] <= i) lo = mid; else hi = mid - 1; }
        estrm[gbase[lo] + (i - exc_[lo])] = buf[i];
    }
}

// ---------- 2. per-bucket two-key counting sort -> CSR + node stats ----------
// col written IN PLACE over estrm (staged through LDS first).
__global__ void __launch_bounds__(256)
binfill3_kernel(unsigned* estrm, const int* __restrict__ ecnt, int n,
                float* __restrict__ rd, float* __restrict__ ird,
                int* __restrict__ rstart, int* __restrict__ rlen, int* col) {
    int b = blockIdx.x;
    int lo = b << 7;
    int nn = min(BNODES, n - lo);
    int base = b * CAP;
    int ec = ecnt[b];
    __shared__ unsigned ebuf[CAP];
    __shared__ int kcnt[NKEY];
    __shared__ int dcnt[BNODES];
    __shared__ int wsum[256];
    int t = threadIdx.x;
    for (int i = t; i < NKEY; i += 256) kcnt[i] = 0;
    if (t < BNODES) dcnt[t] = 0;
    __syncthreads();
    for (int i = t; i < ec; i += 256) {
        unsigned pk = estrm[base + i];
        ebuf[i] = pk;
        int dlo = (int)(pk >> 19);
        int st  = (int)((pk & 0x7FFFF) >> 13);
        atomicAdd(&kcnt[(dlo << 6) | st], 1);
        atomicAdd(&dcnt[dlo], 1);
    }
    __syncthreads();
    // exclusive scan over kcnt[0..NKEY): KPT serial slots + 256-wide scan
    int lsum = 0;
    #pragma unroll
    for (int s = 0; s < KPT; ++s) lsum += kcnt[t * KPT + s];
    wsum[t] = lsum;
    __syncthreads();
    for (int o = 1; o < 256; o <<= 1) {
        int a = (t >= o) ? wsum[t - o] : 0;
        __syncthreads();
        wsum[t] += a;
        __syncthreads();
    }
    int run = (t > 0) ? wsum[t - 1] : 0;
    #pragma unroll
    for (int s = 0; s < KPT; ++s) {
        int idx = t * KPT + s;
        int c = kcnt[idx];
        kcnt[idx] = run;
        run += c;
    }
    __syncthreads();
    if (t < nn) {
        int c = dcnt[t];
        rstart[lo + t] = base + kcnt[t << 6];   // row start = first stratum offset
        rlen[lo + t]   = c;
        rd[lo + t]  = (c > 0) ? rsqrtf((float)c) : 0.0f;
        ird[lo + t] = (c > 0) ? sqrtf((float)c)  : 0.0f;
    }
    __syncthreads();
    // scatter: grouped by dst row, ascending stratum within row
    for (int i = t; i < ec; i += 256) {
        unsigned pk = ebuf[i];
        int key = (int)((pk >> 19) << 6) | (int)((pk & 0x7FFFF) >> 13);
        int p = atomicAdd(&kcnt[key], 1);
        col[base + p] = (int)(pk & 0x7FFFF);
    }
}

// ---------- 3. init y0 = rd .* x0 (fp16) ----------
__global__ void init_kernel(const float* __restrict__ ue, const float* __restrict__ ie,
                            const float* __restrict__ rd, int nu32, int tot32,
                            __half* __restrict__ y0) {
    int gid = blockIdx.x * blockDim.x + threadIdx.x;
    int i2 = gid * 2;
    if (i2 < tot32) {
        float v0 = (i2 < nu32) ? ue[i2] : ie[i2 - nu32];
        float v1 = (i2 < nu32) ? ue[i2 + 1] : ie[i2 + 1 - nu32];   // nu32 even
        float r = rd[i2 >> 5];
        *reinterpret_cast<__half2*>(y0 + i2) = __floats2half2_rn(r * v0, r * v1);
    }
}

// ---------- 4. node-centric CSR gather layer (R7-proven structure) ----------
// 8-lane group per node; lane q holds halves [4q, 4q+4) (8B) of the 64B row.
__global__ void __launch_bounds__(256)
layer_kernel(const int* __restrict__ rstart, const int* __restrict__ rlen,
             const int* __restrict__ col, const float* __restrict__ rd,
             const __half* __restrict__ yin, __half* __restrict__ yout, int n) {
    int gid = blockIdx.x * blockDim.x + threadIdx.x;
    int node = gid >> 3;
    int q = gid & 7;
    if (node >= n) return;
    int e0 = rstart[node];
    int e1 = e0 + rlen[node];
    float4 s = make_float4(0.f, 0.f, 0.f, 0.f);
    for (int base = e0; base < e1; base += 8) {
        int idx = base + q;
        int c = (idx < e1) ? col[idx] : 0;
        int m = min(8, e1 - base);
        for (int j = 0; j < m; ++j) {
            int cj = __shfl(c, j, 8);
            uint2 u = *reinterpret_cast<const uint2*>(yin + (size_t)cj * D + q * 4);
            float2 f0 = __half22float2(*reinterpret_cast<__half2*>(&u.x));
            float2 f1 = __half22float2(*reinterpret_cast<__half2*>(&u.y));
            s.x += f0.x; s.y += f0.y; s.z += f1.x; s.w += f1.y;
        }
    }
    float r = rd[node];
    float r2 = r * r;                 // y_next = rd^2 * sum
    __half2 o0 = __floats2half2_rn(r2 * s.x, r2 * s.y);
    __half2 o1 = __floats2half2_rn(r2 * s.z, r2 * s.w);
    uint2 o;
    o.x = *reinterpret_cast<unsigned*>(&o0);
    o.y = *reinterpret_cast<unsigned*>(&o1);
    *reinterpret_cast<uint2*>(yout + (size_t)node * D + q * 4) = o;
}

// ---------- 5. merge: out = 0.25*(x0 + (y1+y2+y3)*ird) ----------
__global__ void merge_kernel(const float* __restrict__ ue, const float* __restrict__ ie,
                             const float* __restrict__ ird,
                             const __half* __restrict__ y1, const __half* __restrict__ y2,
                             const __half* __restrict__ y3,
                             int nu32, int tot32, float* __restrict__ out) {
    int gid = blockIdx.x * blockDim.x + threadIdx.x;
    int i2 = gid * 2;
    if (i2 < tot32) {
        float v0 = (i2 < nu32) ? ue[i2] : ie[i2 - nu32];
        float v1 = (i2 < nu32) ? ue[i2 + 1] : ie[i2 + 1 - nu32];
        float iv = ird[i2 >> 5];
        float2 a = __half22float2(*reinterpret_cast<const __half2*>(y1 + i2));
        float2 b = __half22float2(*reinterpret_cast<const __half2*>(y2 + i2));
        float2 c = __half22float2(*reinterpret_cast<const __half2*>(y3 + i2));
        float o0 = 0.25f * (v0 + (a.x + b.x + c.x) * iv);
        float o1 = 0.25f * (v1 + (a.y + b.y + c.y) * iv);
        *reinterpret_cast<float2*>(out + i2) = make_float2(o0, o1);
    }
}

static inline char* alloc256(char*& p, size_t bytes) {
    uintptr_t q = ((uintptr_t)p + 255) & ~(uintptr_t)255;
    char* r = (char*)q;
    p = r + bytes;
    return r;
}

extern "C" void kernel_launch(void* const* d_in, const int* in_sizes, int n_in,
                              void* d_out, int out_size, void* d_ws, size_t ws_size,
                              hipStream_t stream) {
    const int*   edge = (const int*)d_in[0];
    const float* ue   = (const float*)d_in[3];
    const float* ie   = (const float*)d_in[4];
    int E  = in_sizes[0] / 2;
    int nu = in_sizes[3] / D;
    int ni = in_sizes[4] / D;
    int n  = nu + ni;
    int nb = (n + BNODES - 1) >> 7;          // 2344 (<= MAXB2)
    const int* src = edge;
    const int* dst = edge + E;
    float* out = (float*)d_out;

    // workspace layout (~87 MB), 256B-aligned
    char* p = (char*)d_ws;
    int*      qcur   = (int*)alloc256(p, (size_t)(MAXB2 + 1) * 4);
    float*    rd     = (float*)alloc256(p, (size_t)n * 4);
    float*    ird    = (float*)alloc256(p, (size_t)n * 4);
    int*      rstart = (int*)alloc256(p, (size_t)n * 4);
    int*      rlen   = (int*)alloc256(p, (size_t)n * 4);
    unsigned* estrm  = (unsigned*)alloc256(p, (size_t)nb * CAP * 4);
    int*      col    = (int*)estrm;          // col overwrites estrm in place
    __half*   yA     = (__half*)alloc256(p, (size_t)n * D * 2);
    __half*   yB     = (__half*)alloc256(p, (size_t)n * D * 2);
    __half*   yC     = (__half*)alloc256(p, (size_t)n * D * 2);

    hipMemsetAsync(qcur, 0, (size_t)(MAXB2 + 1) * 4, stream);

    msplit_kernel<<<(E + TILE - 1) / TILE, 256, 0, stream>>>(src, dst, E, nb, qcur, estrm);
    binfill3_kernel<<<nb, 256, 0, stream>>>(estrm, qcur, n, rd, ird, rstart, rlen, col);

    int tot32 = n * D;
    init_kernel<<<(n * 16 + 255) / 256, 256, 0, stream>>>(ue, ie, rd, nu * D, tot32, yA);

    int tot8 = n * 8;
    layer_kernel<<<(tot8 + 255) / 256, 256, 0, stream>>>(rstart, rlen, col, rd, yA, yB, n);  // y1
    layer_kernel<<<(tot8 + 255) / 256, 256, 0, stream>>>(rstart, rlen, col, rd, yB, yC, n);  // y2
    layer_kernel<<<(tot8 + 255) / 256, 256, 0, stream>>>(rstart, rlen, col, rd, yC, yA, n);  // y3

    merge_kernel<<<(n * 16 + 255) / 256, 256, 0, stream>>>(ue, ie, ird, yB, yC, yA,
                                                           nu * D, tot32, out);
}

// Round 12
// 571.365 us; speedup vs baseline: 7.7537x; 1.1507x over previous
//
#include <hip/hip_runtime.h>
#include <hip/hip_fp16.h>

// LightGCN forward: 3 propagation layers + layer mean.
//
// Pipeline:
//  1. msplit:   COARSE multisplit (bucket = 1024 dst nodes, nb=293) into static
//               CAP regions; 112B per-tile segments stay coalesced (R11 lesson:
//               fine buckets -> 14B segments -> write amplification).
//               packed u32 = (dst&1023)<<19 | src.
//  2. binfill4: one block per bucket; two-key LDS counting sort
//               (key = dlo<<5 | src>>14, 32 strata) -> col row-grouped with
//               src-ascending rows; rstart/rlen/rd/ird. 136KB LDS (R8-proven
//               size). Scatter confined to 69KB window -> L2 line assembly.
//  3. init:     y0 = rd .* x0 (fp16 rows, 64B)
//  4. layer x3: node-centric CSR gather (R7-proven): 8-lane group per node.
//               y_next[i] = rd[i]^2 * sum_{src in row i} y[src]
//               Row-ascending src => all CUs sweep src-space in lockstep ->
//               narrow L2 band (R8-verified FETCH 407->196 MB).
//  5. merge:    out = 0.25*(x0 + (y1+y2+y3)*sqrt(deg))
//
// Sort order is a perf hint only; correctness independent of scheduling.

#define D 32
#define TILE 8192
#define MAXB 512            // >= nb = ceil(300000/1024) = 293
#define CAP 18432           // per-bucket region: mean 17067, sigma 130 -> +10.5
#define NST 32              // src>>14 -> 0..18, padded to 32
#define NKEY4 32768         // 1024 rows x 32 strata
#define KPT4 128            // NKEY4 / 256

// ---------- 1. coarse LDS-staged multisplit ----------
__global__ void __launch_bounds__(256)
msplit_kernel(const int* __restrict__ src, const int* __restrict__ dst, int E, int nb,
              int* __restrict__ qcur, unsigned* __restrict__ estrm) {
    __shared__ unsigned buf[TILE];
    __shared__ int hist[MAXB], exc[MAXB], gbase[MAXB], off[MAXB], sc[MAXB];
    int t = threadIdx.x;
    int tile0 = blockIdx.x * TILE;
    if (tile0 >= E) return;
    int cnt = min(TILE, E - tile0);

    for (int i = t; i < MAXB; i += 256) hist[i] = 0;
    __syncthreads();
    for (int i = t; i < cnt; i += 256)
        atomicAdd(&hist[dst[tile0 + i] >> 10], 1);
    __syncthreads();

    // inclusive scan of hist[0..MAXB) with 256 threads (2 elems each)
    int h0 = hist[t], h1 = hist[t + 256];
    sc[t] = h0; sc[t + 256] = h1;
    __syncthreads();
    for (int o = 1; o < MAXB; o <<= 1) {
        int a0 = (t >= o) ? sc[t - o] : 0;
        int a1 = (t + 256 >= o) ? sc[t + 256 - o] : 0;
        __syncthreads();
        sc[t] += a0; sc[t + 256] += a1;
        __syncthreads();
    }
    exc[t] = sc[t] - h0;
    exc[t + 256] = sc[t + 256] - h1;
    gbase[t]       = (h0 > 0) ? (t * CAP + atomicAdd(&qcur[t], h0))               : 0;
    gbase[t + 256] = (h1 > 0) ? ((t + 256) * CAP + atomicAdd(&qcur[t + 256], h1)) : 0;
    off[t] = exc[t];
    off[t + 256] = exc[t + 256];
    __syncthreads();

    // group tile's edges by bucket in LDS
    for (int i = t; i < cnt; i += 256) {
        int d = dst[tile0 + i];              // L2-warm re-read
        int s = src[tile0 + i];
        int b = d >> 10;
        int pos = atomicAdd(&off[b], 1);
        buf[pos] = ((unsigned)(d & 1023) << 19) | (unsigned)s;
    }
    __syncthreads();

    // copy out: contiguous per-bucket segments (~112B) -> coalesced writes
    for (int i = t; i < cnt; i += 256) {
        int lo = 0, hi = nb - 1;             // largest b with exc[b] <= i
        while (lo < hi) { int mid = (lo + hi + 1) >> 1; if (exc[mid] <= i) lo = mid; else hi = mid - 1; }
        estrm[gbase[lo] + (i - exc[lo])] = buf[i];
    }
}

// ---------- 2. per-bucket two-key counting sort -> CSR + node stats ----------
// Reads estrm twice (2nd pass L2-warm); writes col (separate buffer).
__global__ void __launch_bounds__(256)
binfill4_kernel(const unsigned* __restrict__ estrm, const int* __restrict__ ecnt,
                int n, float* __restrict__ rd, float* __restrict__ ird,
                int* __restrict__ rstart, int* __restrict__ rlen,
                int* __restrict__ col) {
    int b = blockIdx.x;
    int lo = b << 10;
    int nn = min(1024, n - lo);
    int base = b * CAP;
    int ec = ecnt[b];
    __shared__ int kcnt[NKEY4];          // 128 KB
    __shared__ int dcnt[1024];           // 4 KB
    __shared__ int wsum[256];
    int t = threadIdx.x;
    for (int i = t; i < NKEY4; i += 256) kcnt[i] = 0;
    for (int i = t; i < 1024; i += 256) dcnt[i] = 0;
    __syncthreads();
    for (int i = t; i < ec; i += 256) {
        unsigned pk = estrm[base + i];
        int dlo = (int)(pk >> 19);
        int st  = (int)((pk & 0x7FFFF) >> 14);
        atomicAdd(&kcnt[(dlo << 5) | st], 1);
        atomicAdd(&dcnt[dlo], 1);
    }
    __syncthreads();
    // exclusive scan over kcnt[0..NKEY4): KPT4 serial slots + 256-wide scan
    int lsum = 0;
    for (int s = 0; s < KPT4; ++s) lsum += kcnt[t * KPT4 + s];
    wsum[t] = lsum;
    __syncthreads();
    for (int o = 1; o < 256; o <<= 1) {
        int a = (t >= o) ? wsum[t - o] : 0;
        __syncthreads();
        wsum[t] += a;
        __syncthreads();
    }
    int run = (t > 0) ? wsum[t - 1] : 0;
    for (int s = 0; s < KPT4; ++s) {
        int idx = t * KPT4 + s;
        int c = kcnt[idx];
        kcnt[idx] = run;
        run += c;
    }
    __syncthreads();
    for (int i = t; i < nn; i += 256) {
        int c = dcnt[i];
        rstart[lo + i] = base + kcnt[i << 5];   // row start = its first stratum
        rlen[lo + i]   = c;
        rd[lo + i]  = (c > 0) ? rsqrtf((float)c) : 0.0f;
        ird[lo + i] = (c > 0) ? sqrtf((float)c)  : 0.0f;
    }
    __syncthreads();
    // scatter: grouped by dst row, ascending stratum within row; writes stay
    // inside this bucket's ~69KB window (single block -> L2 line assembly)
    for (int i = t; i < ec; i += 256) {
        unsigned pk = estrm[base + i];           // L2-warm re-read
        int key = (int)((pk >> 19) << 5) | (int)((pk & 0x7FFFF) >> 14);
        int p = atomicAdd(&kcnt[key], 1);
        col[base + p] = (int)(pk & 0x7FFFF);
    }
}

// ---------- 3. init y0 = rd .* x0 (fp16) ----------
__global__ void init_kernel(const float* __restrict__ ue, const float* __restrict__ ie,
                            const float* __restrict__ rd, int nu32, int tot32,
                            __half* __restrict__ y0) {
    int gid = blockIdx.x * blockDim.x + threadIdx.x;
    int i2 = gid * 2;
    if (i2 < tot32) {
        float v0 = (i2 < nu32) ? ue[i2] : ie[i2 - nu32];
        float v1 = (i2 < nu32) ? ue[i2 + 1] : ie[i2 + 1 - nu32];   // nu32 even
        float r = rd[i2 >> 5];
        *reinterpret_cast<__half2*>(y0 + i2) = __floats2half2_rn(r * v0, r * v1);
    }
}

// ---------- 4. node-centric CSR gather layer (R7-proven structure) ----------
// 8-lane group per node; lane q holds halves [4q, 4q+4) (8B) of the 64B row.
__global__ void __launch_bounds__(256)
layer_kernel(const int* __restrict__ rstart, const int* __restrict__ rlen,
             const int* __restrict__ col, const float* __restrict__ rd,
             const __half* __restrict__ yin, __half* __restrict__ yout, int n) {
    int gid = blockIdx.x * blockDim.x + threadIdx.x;
    int node = gid >> 3;
    int q = gid & 7;
    if (node >= n) return;
    int e0 = rstart[node];
    int e1 = e0 + rlen[node];
    float4 s = make_float4(0.f, 0.f, 0.f, 0.f);
    for (int base = e0; base < e1; base += 8) {
        int idx = base + q;
        int c = (idx < e1) ? col[idx] : 0;
        int m = min(8, e1 - base);
        for (int j = 0; j < m; ++j) {
            int cj = __shfl(c, j, 8);
            uint2 u = *reinterpret_cast<const uint2*>(yin + (size_t)cj * D + q * 4);
            float2 f0 = __half22float2(*reinterpret_cast<__half2*>(&u.x));
            float2 f1 = __half22float2(*reinterpret_cast<__half2*>(&u.y));
            s.x += f0.x; s.y += f0.y; s.z += f1.x; s.w += f1.y;
        }
    }
    float r = rd[node];
    float r2 = r * r;                 // y_next = rd^2 * sum
    __half2 o0 = __floats2half2_rn(r2 * s.x, r2 * s.y);
    __half2 o1 = __floats2half2_rn(r2 * s.z, r2 * s.w);
    uint2 o;
    o.x = *reinterpret_cast<unsigned*>(&o0);
    o.y = *reinterpret_cast<unsigned*>(&o1);
    *reinterpret_cast<uint2*>(yout + (size_t)node * D + q * 4) = o;
}

// ---------- 5. merge: out = 0.25*(x0 + (y1+y2+y3)*ird) ----------
__global__ void merge_kernel(const float* __restrict__ ue, const float* __restrict__ ie,
                             const float* __restrict__ ird,
                             const __half* __restrict__ y1, const __half* __restrict__ y2,
                             const __half* __restrict__ y3,
                             int nu32, int tot32, float* __restrict__ out) {
    int gid = blockIdx.x * blockDim.x + threadIdx.x;
    int i2 = gid * 2;
    if (i2 < tot32) {
        float v0 = (i2 < nu32) ? ue[i2] : ie[i2 - nu32];
        float v1 = (i2 < nu32) ? ue[i2 + 1] : ie[i2 + 1 - nu32];
        float iv = ird[i2 >> 5];
        float2 a = __half22float2(*reinterpret_cast<const __half2*>(y1 + i2));
        float2 b = __half22float2(*reinterpret_cast<const __half2*>(y2 + i2));
        float2 c = __half22float2(*reinterpret_cast<const __half2*>(y3 + i2));
        float o0 = 0.25f * (v0 + (a.x + b.x + c.x) * iv);
        float o1 = 0.25f * (v1 + (a.y + b.y + c.y) * iv);
        *reinterpret_cast<float2*>(out + i2) = make_float2(o0, o1);
    }
}

static inline char* alloc256(char*& p, size_t bytes) {
    uintptr_t q = ((uintptr_t)p + 255) & ~(uintptr_t)255;
    char* r = (char*)q;
    p = r + bytes;
    return r;
}

extern "C" void kernel_launch(void* const* d_in, const int* in_sizes, int n_in,
                              void* d_out, int out_size, void* d_ws, size_t ws_size,
                              hipStream_t stream) {
    const int*   edge = (const int*)d_in[0];
    const float* ue   = (const float*)d_in[3];
    const float* ie   = (const float*)d_in[4];
    int E  = in_sizes[0] / 2;
    int nu = in_sizes[3] / D;
    int ni = in_sizes[4] / D;
    int n  = nu + ni;
    int nb = (n + 1023) >> 10;               // 293 (<= MAXB)
    const int* src = edge;
    const int* dst = edge + E;
    float* out = (float*)d_out;

    // workspace layout (~105 MB), 256B-aligned
    char* p = (char*)d_ws;
    int*      qcur   = (int*)alloc256(p, (size_t)(MAXB + 1) * 4);
    float*    rd     = (float*)alloc256(p, (size_t)n * 4);
    float*    ird    = (float*)alloc256(p, (size_t)n * 4);
    int*      rstart = (int*)alloc256(p, (size_t)n * 4);
    int*      rlen   = (int*)alloc256(p, (size_t)n * 4);
    unsigned* estrm  = (unsigned*)alloc256(p, (size_t)nb * CAP * 4);
    int*      col    = (int*)alloc256(p, (size_t)nb * CAP * 4);
    __half*   yA     = (__half*)alloc256(p, (size_t)n * D * 2);
    __half*   yB     = (__half*)alloc256(p, (size_t)n * D * 2);
    __half*   yC     = (__half*)alloc256(p, (size_t)n * D * 2);

    hipMemsetAsync(qcur, 0, (size_t)(MAXB + 1) * 4, stream);

    msplit_kernel<<<(E + TILE - 1) / TILE, 256, 0, stream>>>(src, dst, E, nb, qcur, estrm);
    binfill4_kernel<<<nb, 256, 0, stream>>>(estrm, qcur, n, rd, ird, rstart, rlen, col);

    int tot32 = n * D;
    init_kernel<<<(n * 16 + 255) / 256, 256, 0, stream>>>(ue, ie, rd, nu * D, tot32, yA);

    int tot8 = n * 8;
    layer_kernel<<<(tot8 + 255) / 256, 256, 0, stream>>>(rstart, rlen, col, rd, yA, yB, n);  // y1
    layer_kernel<<<(tot8 + 255) / 256, 256, 0, stream>>>(rstart, rlen, col, rd, yB, yC, n);  // y2
    layer_kernel<<<(tot8 + 255) / 256, 256, 0, stream>>>(rstart, rlen, col, rd, yC, yA, n);  // y3

    merge_kernel<<<(n * 16 + 255) / 256, 256, 0, stream>>>(ue, ie, ird, yB, yC, yA,
                                                           nu * D, tot32, out);
}